// Round 10
// baseline (116.820 us; speedup 1.0000x reference)
//
#include <hip/hip_runtime.h>
#include <hip/hip_bf16.h>

static constexpr int NN  = 50000;  // nodes
static constexpr int KNB = 32;     // neighbors
static constexpr int F   = 128;    // features
static constexpr int E   = 8;      // edge features
static constexpr int TI  = 16;     // nodes per block (3125 blocks)
static constexpr int LN  = F * E;  // 1024 contraction length

typedef __attribute__((ext_vector_type(8))) short short8v;
typedef __attribute__((ext_vector_type(4))) float f32x4;

__device__ __forceinline__ unsigned short f2bf(float x) {
    unsigned u = __float_as_uint(x);
    unsigned r = (u + 0x7fff + ((u >> 16) & 1)) >> 16;   // RNE
    return (unsigned short)r;
}

// ---------- prep A: w[l,m,n] -> W2f bf16 in B-fragment order ----------
// W2f[((kb*128 + m)*4 + kq)*8 + e8] = bf16( w[l,m,n] ) where
//   k = kb*32 + kq*4 + (e8&3) + (e8>>2)*16 ,  l = k>>3, n = k&7
__global__ void prep_w_kernel(const float* __restrict__ w, unsigned short* __restrict__ w2f) {
    int o  = blockIdx.x * 256 + threadIdx.x;          // 131072 total
    int e8 = o & 7, kq = (o >> 3) & 3, m = (o >> 5) & 127, kb = o >> 12;
    int k  = kb * 32 + kq * 4 + (e8 & 3) + ((e8 >> 2) << 4);
    int l  = k >> 3, n = k & 7;
    w2f[o] = f2bf(w[(size_t)(l * F + m) * E + n]);
}

// ---------- prep B: nodes fp32 -> bf16 (3125 blocks x 256 thr x 8 elems = exact) ----------
__global__ void prep_nodes_kernel(const float* __restrict__ nodes, unsigned short* __restrict__ nb) {
    int t = blockIdx.x * 256 + threadIdx.x;
    const float4* s = (const float4*)nodes + (size_t)t * 2;
    float4 a = s[0], b = s[1];
    uint4 pk;
    pk.x = (unsigned)f2bf(a.x) | ((unsigned)f2bf(a.y) << 16);
    pk.y = (unsigned)f2bf(a.z) | ((unsigned)f2bf(a.w) << 16);
    pk.z = (unsigned)f2bf(b.x) | ((unsigned)f2bf(b.y) << 16);
    pk.w = (unsigned)f2bf(b.z) | ((unsigned)f2bf(b.w) << 16);
    ((uint4*)nb)[t] = pk;
}

// ---------- main fused kernel ----------
// stage 1: dwordx2 gathers (8B/lane = 512B/wave = TWO neighbor rows per
//   instruction). Lane-half h = lane>>5 owns T-row (2wv+h); c = lane&31 owns
//   columns 4c..4c+3. Edges staged in LDS (per-half divergent). T written
//   bf16 with swizzle slot = (4c+t) ^ (c&7) ^ (row&7)  (conflict-free).
// stage 2: MFMA out[i][m] = inv[i] * sum_ln T[i][ln] * W2[ln][m]; the (c&7)
//   part of the swizzle folds to a compile-time ^(kb&7)<<4 on the read side.
__global__ __launch_bounds__(512, 6)
void mp_main_kernel(const unsigned short* __restrict__ nodesBf,
                    const int*   __restrict__ nlist,
                    const float* __restrict__ edges,
                    const float* __restrict__ inv_degree,
                    const unsigned short* __restrict__ w2f,
                    float* __restrict__ out)
{
    __shared__ unsigned short tS[TI * LN];            // 32 KiB T
    __shared__ float eS[TI * KNB * E];                // 16 KiB staged edges (fp32)
    const int tid    = threadIdx.x;
    const int wv     = __builtin_amdgcn_readfirstlane(tid >> 6);   // wave id 0..7
    const int lane   = tid & 63;
    const int h      = lane >> 5;                     // row half
    const int c      = lane & 31;                     // column group (cols 4c..4c+3)
    const int i_base = blockIdx.x * TI;
    char* tB = (char*)tS;

    // ---- stage edges into LDS (layout == global slice, coalesced) ----
    {
        const float4* src = (const float4*)(edges + (size_t)i_base * (KNB * E));
        float4* dst = (float4*)eS;
        #pragma unroll
        for (int r = 0; r < 8; ++r) dst[r * 512 + tid] = src[r * 512 + tid];
    }
    __syncthreads();

    // ---------------- stage 1: both rows of the wave in one pass ----------------
    {
        const int row = wv * 2 + h;                   // per-lane T-row 0..15
        const int* nlA = nlist + (size_t)(i_base + wv * 2) * KNB;   // uniform
        const int* nlB = nlA + KNB;

        float acc[4][8];
        #pragma unroll
        for (int k = 0; k < 4; ++k)
            #pragma unroll
            for (int n = 0; n < 8; ++n) acc[k][n] = 0.f;

        const unsigned cb = (unsigned)c * 8u;         // byte offset of cols 4c.. in a row
        const float2* ep = (const float2*)(eS + row * (KNB * E));   // per-lane row slice

        #pragma unroll
        for (int j = 0; j < KNB; ++j) {
            unsigned iA = (unsigned)nlA[j]; if (iA >= (unsigned)NN) iA = 0u;  // scalar
            unsigned iB = (unsigned)nlB[j]; if (iB >= (unsigned)NN) iB = 0u;  // scalar
            const unsigned voff = (h ? iB : iA) * 256u + cb;   // cndmask + add
            const uint2 g = *(const uint2*)((const char*)nodesBf + voff);  // dwordx2, 2 rows/wave
            const float2 e01 = ep[j * 4 + 0];         // ds_read_b128 x2 (broadcast/half)
            const float2 e23 = ep[j * 4 + 1];
            const float2 e45 = ep[j * 4 + 2];
            const float2 e67 = ep[j * 4 + 3];
            const float vk[4] = { __uint_as_float(g.x << 16),
                                  __uint_as_float(g.x & 0xffff0000u),
                                  __uint_as_float(g.y << 16),
                                  __uint_as_float(g.y & 0xffff0000u) };
            #pragma unroll
            for (int k = 0; k < 4; ++k) {             // pairs over n -> auto v_pk_fma_f32
                acc[k][0] = __builtin_fmaf(e01.x, vk[k], acc[k][0]);
                acc[k][1] = __builtin_fmaf(e01.y, vk[k], acc[k][1]);
                acc[k][2] = __builtin_fmaf(e23.x, vk[k], acc[k][2]);
                acc[k][3] = __builtin_fmaf(e23.y, vk[k], acc[k][3]);
                acc[k][4] = __builtin_fmaf(e45.x, vk[k], acc[k][4]);
                acc[k][5] = __builtin_fmaf(e45.y, vk[k], acc[k][5]);
                acc[k][6] = __builtin_fmaf(e67.x, vk[k], acc[k][6]);
                acc[k][7] = __builtin_fmaf(e67.y, vk[k], acc[k][7]);
            }
        }

        // write T[row], cols l = 4c+t, bytes l*16 + 2n, swizzled:
        // byte = (l*16) ^ ((c&7)<<4) ^ ((row&7)<<4)  -- conflict-free (8 bankgroups)
        const int sw = ((row & 7) << 4) ^ ((c & 7) << 4);
        const int rb = row * (LN * 2);
        #pragma unroll
        for (int t = 0; t < 4; ++t) {                 // static acc index (rule #20)
            uint4 pk;
            asm("v_cvt_pk_bf16_f32 %0, %1, %2" : "=v"(pk.x) : "v"(acc[t][0]), "v"(acc[t][1]));
            asm("v_cvt_pk_bf16_f32 %0, %1, %2" : "=v"(pk.y) : "v"(acc[t][2]), "v"(acc[t][3]));
            asm("v_cvt_pk_bf16_f32 %0, %1, %2" : "=v"(pk.z) : "v"(acc[t][4]), "v"(acc[t][5]));
            asm("v_cvt_pk_bf16_f32 %0, %1, %2" : "=v"(pk.w) : "v"(acc[t][6]), "v"(acc[t][7]));
            *(uint4*)(tB + rb + ((((c * 4 + t) * 16)) ^ sw)) = pk;
        }
    }
    __syncthreads();

    // ---------------- stage 2: MFMA, one 16x16 m-tile per wave ----------------
    const int colm = lane & 15;                       // i-row for A, m-col for B/C
    const int kq   = lane >> 4;
    const int mt   = wv;                              // m-tile 0..7

    f32x4 c0 = {0.f, 0.f, 0.f, 0.f};

    const int arow = colm * (LN * 2);
    const int asw  = (colm & 7) << 4;                 // row part of swizzle

    #pragma unroll 4
    for (int kb = 0; kb < LN / 32; ++kb) {
        const int lx = (kb & 7) << 4;                 // (l>>2)&7 == kb for both 8B reads
        union { short8v v; uint2 u[2]; } af;
        af.u[0] = *(const uint2*)(tB + arow + ((kb * 64      + kq * 8) ^ asw ^ lx)); // k=kb*32+kq*4+e
        af.u[1] = *(const uint2*)(tB + arow + ((kb * 64 + 32 + kq * 8) ^ asw ^ lx)); // k=kb*32+16+kq*4+e
        union { short8v v; uint4 u; } b0;
        b0.u = *(const uint4*)(w2f + ((size_t)((kb * 128 + mt * 16 + colm) * 4 + kq)) * 8);
        c0 = __builtin_amdgcn_mfma_f32_16x16x32_bf16(af.v, b0.v, c0, 0, 0, 0);
    }

    // C/D: col = lane&15, row = (lane>>4)*4 + r   [measured m89]
    #pragma unroll
    for (int r = 0; r < 4; ++r) {
        const int ii = kq * 4 + r;
        const int gi = i_base + ii;
        out[(size_t)gi * F + mt * 16 + colm] = inv_degree[gi] * c0[r];
    }
}

// ---------- fallback (round-1 kernel, pure fp32) for tiny ws ----------
__global__ __launch_bounds__(256, 2)
void mp_fused_fallback(const float* __restrict__ nodes, const int* __restrict__ nlist,
                       const float* __restrict__ edges, const float* __restrict__ inv_degree,
                       const float* __restrict__ w, float* __restrict__ out)
{
    __shared__ float tLds[TI * F * E];
    const int tid = threadIdx.x;
    const int i_base = blockIdx.x * TI;
    {
        const int l = tid & (F - 1);
        const int half = __builtin_amdgcn_readfirstlane(tid >> 7);
        for (int g = 0; g < TI / 2; ++g) {
            const int ii = g * 2 + half;
            const int i = i_base + ii;
            float acc[E];
            #pragma unroll
            for (int n = 0; n < E; ++n) acc[n] = 0.f;
            const int* nl = nlist + i * KNB;
            const float* ep = edges + (size_t)i * (KNB * E);
            #pragma unroll 4
            for (int j = 0; j < KNB; ++j) {
                unsigned idx = (unsigned)nl[j];
                if (idx >= (unsigned)NN) idx = 0u;
                const float v = nodes[idx * F + l];
                #pragma unroll
                for (int n = 0; n < E; ++n) acc[n] = __builtin_fmaf(ep[j * E + n], v, acc[n]);
            }
            float4* dst = (float4*)&tLds[ii * (F * E) + l * E];
            dst[0] = make_float4(acc[0], acc[1], acc[2], acc[3]);
            dst[1] = make_float4(acc[4], acc[5], acc[6], acc[7]);
        }
    }
    __syncthreads();
    const int m_lo = tid & 63;
    const int q = __builtin_amdgcn_readfirstlane(tid >> 6);
    float accA[TI], accB[TI];
    #pragma unroll
    for (int ii = 0; ii < TI; ++ii) { accA[ii] = 0.f; accB[ii] = 0.f; }
    for (int lq = 0; lq < F / 4; ++lq) {
        const int l = q * (F / 4) + lq;
        const float4* wp0 = (const float4*)&w[(size_t)l * (F * E) + (size_t)m_lo * E];
        const float4* wp1 = (const float4*)&w[(size_t)l * (F * E) + (size_t)(m_lo + 64) * E];
        const float4 w0a = wp0[0], w0b = wp0[1];
        const float4 w1a = wp1[0], w1b = wp1[1];
        #pragma unroll
        for (int ii = 0; ii < TI; ++ii) {
            const float4* tp = (const float4*)&tLds[ii * (F * E) + l * E];
            const float4 ta = tp[0], tb = tp[1];
            float sA = accA[ii], sB = accB[ii];
            sA = __builtin_fmaf(ta.x, w0a.x, sA); sA = __builtin_fmaf(ta.y, w0a.y, sA);
            sA = __builtin_fmaf(ta.z, w0a.z, sA); sA = __builtin_fmaf(ta.w, w0a.w, sA);
            sA = __builtin_fmaf(tb.x, w0b.x, sA); sA = __builtin_fmaf(tb.y, w0b.y, sA);
            sA = __builtin_fmaf(tb.z, w0b.z, sA); sA = __builtin_fmaf(tb.w, w0b.w, sA);
            sB = __builtin_fmaf(ta.x, w1a.x, sB); sB = __builtin_fmaf(ta.y, w1a.y, sB);
            sB = __builtin_fmaf(ta.z, w1a.z, sB); sB = __builtin_fmaf(ta.w, w1a.w, sB);
            sB = __builtin_fmaf(tb.x, w1b.x, sB); sB = __builtin_fmaf(tb.y, w1b.y, sB);
            sB = __builtin_fmaf(tb.z, w1b.z, sB); sB = __builtin_fmaf(tb.w, w1b.w, sB);
            accA[ii] = sA; accB[ii] = sB;
        }
    }
    __syncthreads();
    float* pLds = tLds;
    #pragma unroll
    for (int ii = 0; ii < TI; ++ii) {
        pLds[q * (TI * F) + ii * F + m_lo] = accA[ii];
        pLds[q * (TI * F) + ii * F + m_lo + 64] = accB[ii];
    }
    __syncthreads();
    #pragma unroll
    for (int r = 0; r < (TI * F) / 256; ++r) {
        const int o = r * 256 + tid;
        const int ii = o >> 7;
        const int m = o & (F - 1);
        const float s = pLds[0 * (TI * F) + ii * F + m] + pLds[1 * (TI * F) + ii * F + m]
                      + pLds[2 * (TI * F) + ii * F + m] + pLds[3 * (TI * F) + ii * F + m];
        const int i = i_base + ii;
        out[(size_t)i * F + m] = inv_degree[i] * s;
    }
}

extern "C" void kernel_launch(void* const* d_in, const int* in_sizes, int n_in,
                              void* d_out, int out_size, void* d_ws, size_t ws_size,
                              hipStream_t stream) {
    const float* nodes      = (const float*)d_in[0];
    const int*   nlist      = (const int*)d_in[1];
    const float* edges      = (const float*)d_in[2];
    const float* inv_degree = (const float*)d_in[3];
    const float* w          = (const float*)d_in[4];
    float* out = (float*)d_out;
    (void)in_sizes; (void)n_in; (void)out_size;

    const size_t need_w2 = (size_t)LN * F * 2;                  // 256 KiB
    const size_t need_nb = (size_t)NN * F * 2;                  // 12.8 MiB

    if (ws_size < need_w2 + need_nb) {
        mp_fused_fallback<<<dim3(NN / TI), dim3(256), 0, stream>>>(
            nodes, nlist, edges, inv_degree, w, out);
        return;
    }
    unsigned short* w2f = (unsigned short*)d_ws;
    unsigned short* nb  = (unsigned short*)((char*)d_ws + need_w2);

    prep_w_kernel<<<dim3((LN * F) / 256), dim3(256), 0, stream>>>(w, w2f);
    prep_nodes_kernel<<<dim3(NN * F / 8 / 256), dim3(256), 0, stream>>>(nodes, nb);
    mp_main_kernel<<<dim3(NN / TI), dim3(512), 0, stream>>>(
        nb, nlist, edges, inv_degree, w2f, out);
}

// Round 11
// 113.697 us; speedup vs baseline: 1.0275x; 1.0275x over previous
//
#include <hip/hip_runtime.h>
#include <hip/hip_bf16.h>

static constexpr int NN  = 50000;  // nodes
static constexpr int KNB = 32;     // neighbors
static constexpr int F   = 128;    // features
static constexpr int E   = 8;      // edge features
static constexpr int TI  = 16;     // nodes per block (3125 blocks)
static constexpr int LN  = F * E;  // 1024 contraction length

typedef __attribute__((ext_vector_type(8))) short short8v;
typedef __attribute__((ext_vector_type(4))) float f32x4;

__device__ __forceinline__ unsigned short f2bf(float x) {
    unsigned u = __float_as_uint(x);
    unsigned r = (u + 0x7fff + ((u >> 16) & 1)) >> 16;   // RNE
    return (unsigned short)r;
}
__device__ __forceinline__ float bf2f_lo(unsigned g) { return __uint_as_float(g << 16); }
__device__ __forceinline__ float bf2f_hi(unsigned g) { return __uint_as_float(g & 0xffff0000u); }

// async global->LDS, 4B/lane: LDS dest = uniform base + lane*4 (HW rule),
// global src = per-lane address. Fire-and-forget, tracked by vmcnt only.
__device__ __forceinline__ void gload_lds4(const unsigned* gsrc, unsigned* ldst) {
    __builtin_amdgcn_global_load_lds(
        (const __attribute__((address_space(1))) unsigned*)gsrc,
        (__attribute__((address_space(3))) unsigned*)ldst, 4, 0, 0);
}

// ---------- prep A: w[l,m,n] -> W2f bf16 in B-fragment order ----------
// W2f[((kb*128 + m)*4 + kq)*8 + e8] = bf16( w[l,m,n] ) where
//   k = kb*32 + kq*4 + (e8&3) + (e8>>2)*16 ,  l = k>>3, n = k&7
__global__ void prep_w_kernel(const float* __restrict__ w, unsigned short* __restrict__ w2f) {
    int o  = blockIdx.x * 256 + threadIdx.x;          // 131072 total
    int e8 = o & 7, kq = (o >> 3) & 3, m = (o >> 5) & 127, kb = o >> 12;
    int k  = kb * 32 + kq * 4 + (e8 & 3) + ((e8 >> 2) << 4);
    int l  = k >> 3, n = k & 7;
    w2f[o] = f2bf(w[(size_t)(l * F + m) * E + n]);
}

// ---------- prep B: nodes fp32 -> bf16 (3125 blocks x 256 thr x 8 elems = exact) ----------
__global__ void prep_nodes_kernel(const float* __restrict__ nodes, unsigned short* __restrict__ nb) {
    int t = blockIdx.x * 256 + threadIdx.x;
    const float4* s = (const float4*)nodes + (size_t)t * 2;
    float4 a = s[0], b = s[1];
    uint4 pk;
    pk.x = (unsigned)f2bf(a.x) | ((unsigned)f2bf(a.y) << 16);
    pk.y = (unsigned)f2bf(a.z) | ((unsigned)f2bf(a.w) << 16);
    pk.z = (unsigned)f2bf(b.x) | ((unsigned)f2bf(b.y) << 16);
    pk.w = (unsigned)f2bf(b.z) | ((unsigned)f2bf(b.w) << 16);
    ((uint4*)nb)[t] = pk;
}

// ---------- main fused kernel ----------
// R7 structure (512 thr / 8 waves, T 32 KiB, stage-2 unchanged) with stage-1
// gathers via global_load_lds into 2 KiB/wave double-buffered staging:
// 16 chunks x 4 rows, 1-ahead prefetch, counted s_waitcnt vmcnt(4) (never 0
// until the tail) -> 4-8 gathers in flight per wave at zero VGPR cost.
__global__ __launch_bounds__(512, 6)
void mp_main_kernel(const unsigned short* __restrict__ nodesBf,
                    const int*   __restrict__ nlist,
                    const float* __restrict__ edges,
                    const float* __restrict__ inv_degree,
                    const unsigned short* __restrict__ w2f,
                    float* __restrict__ out)
{
    __shared__ unsigned short tS[TI * LN];            // 32 KiB T (swizzled, R7 layout)
    __shared__ unsigned stgW[8][2][4 * 64];           // 16 KiB: 8 waves x 2 bufs x 4 rows x 256B
    const int tid    = threadIdx.x;
    const int wv     = __builtin_amdgcn_readfirstlane(tid >> 6);   // wave id 0..7
    const int lane   = tid & 63;
    const int i_base = blockIdx.x * TI;
    char* tB = (char*)tS;

    // ---------------- stage 1: rows {2wv, 2wv+1}, 16 chunks of 4 gathers ----------------
    {
        const int i0 = i_base + wv * 2;
        const int*   nl = nlist + (size_t)i0 * KNB;   // 64 indices, both rows contiguous
        const float* ep = edges + (size_t)i0 * (KNB * E);

        // chunk c covers global j' = 4c..4c+3 (j' = row*32 + j); row = c>>3
        auto issue = [&](int c) {
            const int* nlr = nl + c * 4;
            unsigned* dst = &stgW[wv][c & 1][0];
            #pragma unroll
            for (int q = 0; q < 4; ++q) {
                unsigned idx = (unsigned)nlr[q];      // wave-uniform -> s_load
                if (idx >= (unsigned)NN) idx = 0u;
                gload_lds4((const unsigned*)(nodesBf + (size_t)idx * F) + lane, dst + q * 64);
            }
        };

        float a0[E], a1[E];
        #pragma unroll
        for (int n = 0; n < E; ++n) { a0[n] = 0.f; a1[n] = 0.f; }

        auto store_row = [&](int row) {
            uint4 pk0, pk1;
            asm("v_cvt_pk_bf16_f32 %0, %1, %2" : "=v"(pk0.x) : "v"(a0[0]), "v"(a0[1]));
            asm("v_cvt_pk_bf16_f32 %0, %1, %2" : "=v"(pk0.y) : "v"(a0[2]), "v"(a0[3]));
            asm("v_cvt_pk_bf16_f32 %0, %1, %2" : "=v"(pk0.z) : "v"(a0[4]), "v"(a0[5]));
            asm("v_cvt_pk_bf16_f32 %0, %1, %2" : "=v"(pk0.w) : "v"(a0[6]), "v"(a0[7]));
            asm("v_cvt_pk_bf16_f32 %0, %1, %2" : "=v"(pk1.x) : "v"(a1[0]), "v"(a1[1]));
            asm("v_cvt_pk_bf16_f32 %0, %1, %2" : "=v"(pk1.y) : "v"(a1[2]), "v"(a1[3]));
            asm("v_cvt_pk_bf16_f32 %0, %1, %2" : "=v"(pk1.z) : "v"(a1[4]), "v"(a1[5]));
            asm("v_cvt_pk_bf16_f32 %0, %1, %2" : "=v"(pk1.w) : "v"(a1[6]), "v"(a1[7]));
            const int p2 = (lane >> 2) & 1;
            const int s  = (row & 7) << 4;
            const int rb = row * (LN * 2);
            const uint4 first  = p2 ? pk1 : pk0;
            const uint4 second = p2 ? pk0 : pk1;
            *(uint4*)(tB + rb + ((lane * 32 + (p2 << 4))      ^ s)) = first;
            *(uint4*)(tB + rb + ((lane * 32 + 16 - (p2 << 4)) ^ s)) = second;
            #pragma unroll
            for (int n = 0; n < E; ++n) { a0[n] = 0.f; a1[n] = 0.f; }
        };

        issue(0);
        issue(1);
        #pragma unroll
        for (int c = 0; c < 16; ++c) {
            if (c + 2 < 16) issue(c + 2);
            if (c < 15) { asm volatile("s_waitcnt vmcnt(8)" ::: "memory"); }
            else        { asm volatile("s_waitcnt vmcnt(0)" ::: "memory"); }
            // NOTE: with 3 chunks in flight the buffer would collide; 2-buf +
            // issue(c+2) means chunk c+2 writes buf (c&1) while we consume it.
            // -> use 1-ahead only: guard above issues c+2 but waits vmcnt(8)
            //    ensure chunk c complete; chunk c+2 targets the OTHER buffer
            //    only when (c+2)&1 != c&1, which is true (c+2 same parity!) —
            //    so we must NOT issue c+2. Corrected below to 1-ahead.
            const unsigned* sb = &stgW[wv][c & 1][0];
            const float* epc = ep + (c * 4) * E;
            #pragma unroll
            for (int q = 0; q < 4; ++q) {
                const unsigned g = sb[q * 64 + lane];
                const float v0 = bf2f_lo(g), v1 = bf2f_hi(g);
                const float4 e0 = *(const float4*)(epc + q * 8);      // uniform -> s_load
                const float4 e1 = *(const float4*)(epc + q * 8 + 4);
                a0[0] = __builtin_fmaf(e0.x, v0, a0[0]); a1[0] = __builtin_fmaf(e0.x, v1, a1[0]);
                a0[1] = __builtin_fmaf(e0.y, v0, a0[1]); a1[1] = __builtin_fmaf(e0.y, v1, a1[1]);
                a0[2] = __builtin_fmaf(e0.z, v0, a0[2]); a1[2] = __builtin_fmaf(e0.z, v1, a1[2]);
                a0[3] = __builtin_fmaf(e0.w, v0, a0[3]); a1[3] = __builtin_fmaf(e0.w, v1, a1[3]);
                a0[4] = __builtin_fmaf(e1.x, v0, a0[4]); a1[4] = __builtin_fmaf(e1.x, v1, a1[4]);
                a0[5] = __builtin_fmaf(e1.y, v0, a0[5]); a1[5] = __builtin_fmaf(e1.y, v1, a1[5]);
                a0[6] = __builtin_fmaf(e1.z, v0, a0[6]); a1[6] = __builtin_fmaf(e1.z, v1, a1[6]);
                a0[7] = __builtin_fmaf(e1.w, v0, a0[7]); a1[7] = __builtin_fmaf(e1.w, v1, a1[7]);
            }
            if (c == 7)  store_row(wv * 2);
            if (c == 15) store_row(wv * 2 + 1);
        }
    }
    __syncthreads();

    // ---------------- stage 2: MFMA, one 16x16 m-tile per wave (R7 verbatim) ----------------
    const int colm = lane & 15;                       // i-row for A, m-col for B/C
    const int kq   = lane >> 4;
    const int mt   = wv;                              // m-tile 0..7

    f32x4 c0 = {0.f, 0.f, 0.f, 0.f};

    const int arow = colm * (LN * 2);
    const int asw  = (colm & 7) << 4;

    #pragma unroll 4
    for (int kb = 0; kb < LN / 32; ++kb) {
        union { short8v v; uint2 u[2]; } af;
        af.u[0] = *(const uint2*)(tB + arow + ((kb * 64      + kq * 8) ^ asw)); // k=kb*32+kq*4+e
        af.u[1] = *(const uint2*)(tB + arow + ((kb * 64 + 32 + kq * 8) ^ asw)); // k=kb*32+16+kq*4+e
        union { short8v v; uint4 u; } b0;
        b0.u = *(const uint4*)(w2f + ((size_t)((kb * 128 + mt * 16 + colm) * 4 + kq)) * 8);
        c0 = __builtin_amdgcn_mfma_f32_16x16x32_bf16(af.v, b0.v, c0, 0, 0, 0);
    }

    // C/D: col = lane&15, row = (lane>>4)*4 + r   [measured m89]
    #pragma unroll
    for (int r = 0; r < 4; ++r) {
        const int ii = kq * 4 + r;
        const int gi = i_base + ii;
        out[(size_t)gi * F + mt * 16 + colm] = inv_degree[gi] * c0[r];
    }
}

// NOTE on the pipeline above: issue(c+2) + 2 buffers would race (same parity
// buffer). The loop body was corrected to 1-ahead semantics by construction:
// prologue issues chunks 0 and 1; at iteration c we issue c+2 ONLY if it does
// not collide — but (c+2)&1 == c&1 ALWAYS collides. Therefore the issue(c+2)
// call above is a bug. The shipped kernel below replaces mp_main_kernel's
// K-loop with the safe 1-ahead version via this macro-free re-definition.
// (Kept as a single kernel: see mp_main_kernel2 used in kernel_launch.)
__global__ __launch_bounds__(512, 6)
void mp_main_kernel2(const unsigned short* __restrict__ nodesBf,
                     const int*   __restrict__ nlist,
                     const float* __restrict__ edges,
                     const float* __restrict__ inv_degree,
                     const unsigned short* __restrict__ w2f,
                     float* __restrict__ out)
{
    __shared__ unsigned short tS[TI * LN];            // 32 KiB
    __shared__ unsigned stgW[8][2][4 * 64];           // 16 KiB
    const int tid    = threadIdx.x;
    const int wv     = __builtin_amdgcn_readfirstlane(tid >> 6);
    const int lane   = tid & 63;
    const int i_base = blockIdx.x * TI;
    char* tB = (char*)tS;

    {
        const int i0 = i_base + wv * 2;
        const int*   nl = nlist + (size_t)i0 * KNB;
        const float* ep = edges + (size_t)i0 * (KNB * E);

        auto issue = [&](int c) {
            const int* nlr = nl + c * 4;
            unsigned* dst = &stgW[wv][c & 1][0];
            #pragma unroll
            for (int q = 0; q < 4; ++q) {
                unsigned idx = (unsigned)nlr[q];
                if (idx >= (unsigned)NN) idx = 0u;
                gload_lds4((const unsigned*)(nodesBf + (size_t)idx * F) + lane, dst + q * 64);
            }
        };

        float a0[E], a1[E];
        #pragma unroll
        for (int n = 0; n < E; ++n) { a0[n] = 0.f; a1[n] = 0.f; }

        auto store_row = [&](int row) {
            uint4 pk0, pk1;
            asm("v_cvt_pk_bf16_f32 %0, %1, %2" : "=v"(pk0.x) : "v"(a0[0]), "v"(a0[1]));
            asm("v_cvt_pk_bf16_f32 %0, %1, %2" : "=v"(pk0.y) : "v"(a0[2]), "v"(a0[3]));
            asm("v_cvt_pk_bf16_f32 %0, %1, %2" : "=v"(pk0.z) : "v"(a0[4]), "v"(a0[5]));
            asm("v_cvt_pk_bf16_f32 %0, %1, %2" : "=v"(pk0.w) : "v"(a0[6]), "v"(a0[7]));
            asm("v_cvt_pk_bf16_f32 %0, %1, %2" : "=v"(pk1.x) : "v"(a1[0]), "v"(a1[1]));
            asm("v_cvt_pk_bf16_f32 %0, %1, %2" : "=v"(pk1.y) : "v"(a1[2]), "v"(a1[3]));
            asm("v_cvt_pk_bf16_f32 %0, %1, %2" : "=v"(pk1.z) : "v"(a1[4]), "v"(a1[5]));
            asm("v_cvt_pk_bf16_f32 %0, %1, %2" : "=v"(pk1.w) : "v"(a1[6]), "v"(a1[7]));
            const int p2 = (lane >> 2) & 1;
            const int s  = (row & 7) << 4;
            const int rb = row * (LN * 2);
            const uint4 first  = p2 ? pk1 : pk0;
            const uint4 second = p2 ? pk0 : pk1;
            *(uint4*)(tB + rb + ((lane * 32 + (p2 << 4))      ^ s)) = first;
            *(uint4*)(tB + rb + ((lane * 32 + 16 - (p2 << 4)) ^ s)) = second;
            #pragma unroll
            for (int n = 0; n < E; ++n) { a0[n] = 0.f; a1[n] = 0.f; }
        };

        issue(0);
        #pragma unroll
        for (int c = 0; c < 16; ++c) {
            if (c + 1 < 16) {
                issue(c + 1);                              // other buffer, in flight
                asm volatile("s_waitcnt vmcnt(4)" ::: "memory");  // chunk c landed
            } else {
                asm volatile("s_waitcnt vmcnt(0)" ::: "memory");
            }
            const unsigned* sb = &stgW[wv][c & 1][0];
            const float* epc = ep + (c * 4) * E;
            #pragma unroll
            for (int q = 0; q < 4; ++q) {
                const unsigned g = sb[q * 64 + lane];
                const float v0 = bf2f_lo(g), v1 = bf2f_hi(g);
                const float4 e0 = *(const float4*)(epc + q * 8);
                const float4 e1 = *(const float4*)(epc + q * 8 + 4);
                a0[0] = __builtin_fmaf(e0.x, v0, a0[0]); a1[0] = __builtin_fmaf(e0.x, v1, a1[0]);
                a0[1] = __builtin_fmaf(e0.y, v0, a0[1]); a1[1] = __builtin_fmaf(e0.y, v1, a1[1]);
                a0[2] = __builtin_fmaf(e0.z, v0, a0[2]); a1[2] = __builtin_fmaf(e0.z, v1, a1[2]);
                a0[3] = __builtin_fmaf(e0.w, v0, a0[3]); a1[3] = __builtin_fmaf(e0.w, v1, a1[3]);
                a0[4] = __builtin_fmaf(e1.x, v0, a0[4]); a1[4] = __builtin_fmaf(e1.x, v1, a1[4]);
                a0[5] = __builtin_fmaf(e1.y, v0, a0[5]); a1[5] = __builtin_fmaf(e1.y, v1, a1[5]);
                a0[6] = __builtin_fmaf(e1.z, v0, a0[6]); a1[6] = __builtin_fmaf(e1.z, v1, a1[6]);
                a0[7] = __builtin_fmaf(e1.w, v0, a0[7]); a1[7] = __builtin_fmaf(e1.w, v1, a1[7]);
            }
            if (c == 7)  store_row(wv * 2);
            if (c == 15) store_row(wv * 2 + 1);
        }
    }
    __syncthreads();

    const int colm = lane & 15;
    const int kq   = lane >> 4;
    const int mt   = wv;

    f32x4 c0 = {0.f, 0.f, 0.f, 0.f};
    const int arow = colm * (LN * 2);
    const int asw  = (colm & 7) << 4;

    #pragma unroll 4
    for (int kb = 0; kb < LN / 32; ++kb) {
        union { short8v v; uint2 u[2]; } af;
        af.u[0] = *(const uint2*)(tB + arow + ((kb * 64      + kq * 8) ^ asw));
        af.u[1] = *(const uint2*)(tB + arow + ((kb * 64 + 32 + kq * 8) ^ asw));
        union { short8v v; uint4 u; } b0;
        b0.u = *(const uint4*)(w2f + ((size_t)((kb * 128 + mt * 16 + colm) * 4 + kq)) * 8);
        c0 = __builtin_amdgcn_mfma_f32_16x16x32_bf16(af.v, b0.v, c0, 0, 0, 0);
    }

    #pragma unroll
    for (int r = 0; r < 4; ++r) {
        const int ii = kq * 4 + r;
        const int gi = i_base + ii;
        out[(size_t)gi * F + mt * 16 + colm] = inv_degree[gi] * c0[r];
    }
}

// ---------- fallback (round-1 kernel, pure fp32) for tiny ws ----------
__global__ __launch_bounds__(256, 2)
void mp_fused_fallback(const float* __restrict__ nodes, const int* __restrict__ nlist,
                       const float* __restrict__ edges, const float* __restrict__ inv_degree,
                       const float* __restrict__ w, float* __restrict__ out)
{
    __shared__ float tLds[TI * F * E];
    const int tid = threadIdx.x;
    const int i_base = blockIdx.x * TI;
    {
        const int l = tid & (F - 1);
        const int half = __builtin_amdgcn_readfirstlane(tid >> 7);
        for (int g = 0; g < TI / 2; ++g) {
            const int ii = g * 2 + half;
            const int i = i_base + ii;
            float acc[E];
            #pragma unroll
            for (int n = 0; n < E; ++n) acc[n] = 0.f;
            const int* nl = nlist + i * KNB;
            const float* ep = edges + (size_t)i * (KNB * E);
            #pragma unroll 4
            for (int j = 0; j < KNB; ++j) {
                unsigned idx = (unsigned)nl[j];
                if (idx >= (unsigned)NN) idx = 0u;
                const float v = nodes[idx * F + l];
                #pragma unroll
                for (int n = 0; n < E; ++n) acc[n] = __builtin_fmaf(ep[j * E + n], v, acc[n]);
            }
            float4* dst = (float4*)&tLds[ii * (F * E) + l * E];
            dst[0] = make_float4(acc[0], acc[1], acc[2], acc[3]);
            dst[1] = make_float4(acc[4], acc[5], acc[6], acc[7]);
        }
    }
    __syncthreads();
    const int m_lo = tid & 63;
    const int q = __builtin_amdgcn_readfirstlane(tid >> 6);
    float accA[TI], accB[TI];
    #pragma unroll
    for (int ii = 0; ii < TI; ++ii) { accA[ii] = 0.f; accB[ii] = 0.f; }
    for (int lq = 0; lq < F / 4; ++lq) {
        const int l = q * (F / 4) + lq;
        const float4* wp0 = (const float4*)&w[(size_t)l * (F * E) + (size_t)m_lo * E];
        const float4* wp1 = (const float4*)&w[(size_t)l * (F * E) + (size_t)(m_lo + 64) * E];
        const float4 w0a = wp0[0], w0b = wp0[1];
        const float4 w1a = wp1[0], w1b = wp1[1];
        #pragma unroll
        for (int ii = 0; ii < TI; ++ii) {
            const float4* tp = (const float4*)&tLds[ii * (F * E) + l * E];
            const float4 ta = tp[0], tb = tp[1];
            float sA = accA[ii], sB = accB[ii];
            sA = __builtin_fmaf(ta.x, w0a.x, sA); sA = __builtin_fmaf(ta.y, w0a.y, sA);
            sA = __builtin_fmaf(ta.z, w0a.z, sA); sA = __builtin_fmaf(ta.w, w0a.w, sA);
            sA = __builtin_fmaf(tb.x, w0b.x, sA); sA = __builtin_fmaf(tb.y, w0b.y, sA);
            sA = __builtin_fmaf(tb.z, w0b.z, sA); sA = __builtin_fmaf(tb.w, w0b.w, sA);
            sB = __builtin_fmaf(ta.x, w1a.x, sB); sB = __builtin_fmaf(ta.y, w1a.y, sB);
            sB = __builtin_fmaf(ta.z, w1a.z, sB); sB = __builtin_fmaf(ta.w, w1a.w, sB);
            sB = __builtin_fmaf(tb.x, w1b.x, sB); sB = __builtin_fmaf(tb.y, w1b.y, sB);
            sB = __builtin_fmaf(tb.z, w1b.z, sB); sB = __builtin_fmaf(tb.w, w1b.w, sB);
            accA[ii] = sA; accB[ii] = sB;
        }
    }
    __syncthreads();
    float* pLds = tLds;
    #pragma unroll
    for (int ii = 0; ii < TI; ++ii) {
        pLds[q * (TI * F) + ii * F + m_lo] = accA[ii];
        pLds[q * (TI * F) + ii * F + m_lo + 64] = accB[ii];
    }
    __syncthreads();
    #pragma unroll
    for (int r = 0; r < (TI * F) / 256; ++r) {
        const int o = r * 256 + tid;
        const int ii = o >> 7;
        const int m = o & (F - 1);
        const float s = pLds[0 * (TI * F) + ii * F + m] + pLds[1 * (TI * F) + ii * F + m]
                      + pLds[2 * (TI * F) + ii * F + m] + pLds[3 * (TI * F) + ii * F + m];
        const int i = i_base + ii;
        out[(size_t)i * F + m] = inv_degree[i] * s;
    }
}

extern "C" void kernel_launch(void* const* d_in, const int* in_sizes, int n_in,
                              void* d_out, int out_size, void* d_ws, size_t ws_size,
                              hipStream_t stream) {
    const float* nodes      = (const float*)d_in[0];
    const int*   nlist      = (const int*)d_in[1];
    const float* edges      = (const float*)d_in[2];
    const float* inv_degree = (const float*)d_in[3];
    const float* w          = (const float*)d_in[4];
    float* out = (float*)d_out;
    (void)in_sizes; (void)n_in; (void)out_size;

    const size_t need_w2 = (size_t)LN * F * 2;                  // 256 KiB
    const size_t need_nb = (size_t)NN * F * 2;                  // 12.8 MiB

    if (ws_size < need_w2 + need_nb) {
        mp_fused_fallback<<<dim3(NN / TI), dim3(256), 0, stream>>>(
            nodes, nlist, edges, inv_degree, w, out);
        return;
    }
    unsigned short* w2f = (unsigned short*)d_ws;
    unsigned short* nb  = (unsigned short*)((char*)d_ws + need_w2);

    prep_w_kernel<<<dim3((LN * F) / 256), dim3(256), 0, stream>>>(w, w2f);
    prep_nodes_kernel<<<dim3(NN * F / 8 / 256), dim3(256), 0, stream>>>(nodes, nb);
    mp_main_kernel2<<<dim3(NN / TI), dim3(512), 0, stream>>>(
        nb, nlist, edges, inv_degree, w2f, out);
}

// Round 13
// 102.742 us; speedup vs baseline: 1.1370x; 1.1066x over previous
//
#include <hip/hip_runtime.h>
#include <hip/hip_bf16.h>

static constexpr int NN  = 50000;  // nodes
static constexpr int KNB = 32;     // neighbors
static constexpr int F   = 128;    // features
static constexpr int E   = 8;      // edge features
static constexpr int TI  = 16;     // nodes per block (3125 blocks)
static constexpr int LN  = F * E;  // 1024 contraction length

typedef __attribute__((ext_vector_type(8))) short short8v;
typedef __attribute__((ext_vector_type(4))) float f32x4;

__device__ __forceinline__ unsigned short f2bf(float x) {
    unsigned u = __float_as_uint(x);
    unsigned r = (u + 0x7fff + ((u >> 16) & 1)) >> 16;   // RNE
    return (unsigned short)r;
}
__device__ __forceinline__ float bf2f_lo(unsigned g) { return __uint_as_float(g << 16); }
__device__ __forceinline__ float bf2f_hi(unsigned g) { return __uint_as_float(g & 0xffff0000u); }

// ---------- prep A: w[l,m,n] -> W2f bf16 in B-fragment order ----------
// W2f[((kb*128 + m)*4 + kq)*8 + e8] = bf16( w[l,m,n] ) where
//   k = kb*32 + kq*4 + (e8&3) + (e8>>2)*16 ,  l = k>>3, n = k&7
__global__ void prep_w_kernel(const float* __restrict__ w, unsigned short* __restrict__ w2f) {
    int o  = blockIdx.x * 256 + threadIdx.x;          // 131072 total
    int e8 = o & 7, kq = (o >> 3) & 3, m = (o >> 5) & 127, kb = o >> 12;
    int k  = kb * 32 + kq * 4 + (e8 & 3) + ((e8 >> 2) << 4);
    int l  = k >> 3, n = k & 7;
    w2f[o] = f2bf(w[(size_t)(l * F + m) * E + n]);
}

// ---------- prep B: nodes fp32 -> bf16 (3125 blocks x 256 thr x 8 elems = exact) ----------
__global__ void prep_nodes_kernel(const float* __restrict__ nodes, unsigned short* __restrict__ nb) {
    int t = blockIdx.x * 256 + threadIdx.x;
    const float4* s = (const float4*)nodes + (size_t)t * 2;
    float4 a = s[0], b = s[1];
    uint4 pk;
    pk.x = (unsigned)f2bf(a.x) | ((unsigned)f2bf(a.y) << 16);
    pk.y = (unsigned)f2bf(a.z) | ((unsigned)f2bf(a.w) << 16);
    pk.z = (unsigned)f2bf(b.x) | ((unsigned)f2bf(b.y) << 16);
    pk.w = (unsigned)f2bf(b.z) | ((unsigned)f2bf(b.w) << 16);
    ((uint4*)nb)[t] = pk;
}

// Early-clobber ("=&v") is REQUIRED: multi-instruction asm; without it an
// output may alias a later instruction's address input (R12 crash).
#define ISSUE8(B)                                                          \
    asm volatile(                                                          \
        "global_load_dword %0, %8, %16\n\t"                                \
        "global_load_dword %1, %9, %16\n\t"                                \
        "global_load_dword %2, %10, %16\n\t"                               \
        "global_load_dword %3, %11, %16\n\t"                               \
        "global_load_dword %4, %12, %16\n\t"                               \
        "global_load_dword %5, %13, %16\n\t"                               \
        "global_load_dword %6, %14, %16\n\t"                               \
        "global_load_dword %7, %15, %16"                                   \
        : "=&v"(g[(B)+0]), "=&v"(g[(B)+1]), "=&v"(g[(B)+2]), "=&v"(g[(B)+3]), \
          "=&v"(g[(B)+4]), "=&v"(g[(B)+5]), "=&v"(g[(B)+6]), "=&v"(g[(B)+7])  \
        : "v"(vo[0]), "v"(vo[1]), "v"(vo[2]), "v"(vo[3]),                  \
          "v"(vo[4]), "v"(vo[5]), "v"(vo[6]), "v"(vo[7]),                  \
          "s"(nodesBf)                                                     \
        : "memory")

#define MKVO(B)                                                            \
    _Pragma("unroll")                                                      \
    for (int q = 0; q < 8; ++q) {                                          \
        unsigned idx = (unsigned)nl[(B) + q];      /* uniform -> s_load */ \
        if (idx >= (unsigned)NN) idx = 0u;                                 \
        vo[q] = idx * 256u + lane4;                                        \
    }

#define WAIT8(NSTR, B)                                                     \
    asm volatile("s_waitcnt vmcnt(" NSTR ")"                               \
        : "+v"(g[(B)+0]), "+v"(g[(B)+1]), "+v"(g[(B)+2]), "+v"(g[(B)+3]),  \
          "+v"(g[(B)+4]), "+v"(g[(B)+5]), "+v"(g[(B)+6]), "+v"(g[(B)+7])   \
        :: "memory")

#define CONSUME8(B)                                                        \
    _Pragma("unroll")                                                      \
    for (int q = 0; q < 8; ++q) {                                          \
        const int j = (B) + q;                                             \
        const float v0 = bf2f_lo(g[(B) + q]);                              \
        const float v1 = bf2f_hi(g[(B) + q]);                              \
        const float4 e0 = *(const float4*)(ep + j * 8);   /* uniform */    \
        const float4 e1 = *(const float4*)(ep + j * 8 + 4);                \
        a0[0] = __builtin_fmaf(e0.x, v0, a0[0]); a1[0] = __builtin_fmaf(e0.x, v1, a1[0]); \
        a0[1] = __builtin_fmaf(e0.y, v0, a0[1]); a1[1] = __builtin_fmaf(e0.y, v1, a1[1]); \
        a0[2] = __builtin_fmaf(e0.z, v0, a0[2]); a1[2] = __builtin_fmaf(e0.z, v1, a1[2]); \
        a0[3] = __builtin_fmaf(e0.w, v0, a0[3]); a1[3] = __builtin_fmaf(e0.w, v1, a1[3]); \
        a0[4] = __builtin_fmaf(e1.x, v0, a0[4]); a1[4] = __builtin_fmaf(e1.x, v1, a1[4]); \
        a0[5] = __builtin_fmaf(e1.y, v0, a0[5]); a1[5] = __builtin_fmaf(e1.y, v1, a1[5]); \
        a0[6] = __builtin_fmaf(e1.z, v0, a0[6]); a1[6] = __builtin_fmaf(e1.z, v1, a1[6]); \
        a0[7] = __builtin_fmaf(e1.w, v0, a0[7]); a1[7] = __builtin_fmaf(e1.w, v1, a1[7]); \
    }

// ---------- main fused kernel ----------
// R7 structure (512 thr / 8 waves, T 32 KiB swizzled, stage-2 verbatim).
// Stage 1: per row, 4 asm bursts of 8 global_load_dword with a rolling
// 24-deep in-flight window (counted vmcnt(16)/(8)/(0), never premature).
__global__ __launch_bounds__(512, 6)
void mp_main_kernel(const unsigned short* __restrict__ nodesBf,
                    const int*   __restrict__ nlist,
                    const float* __restrict__ edges,
                    const float* __restrict__ inv_degree,
                    const unsigned short* __restrict__ w2f,
                    float* __restrict__ out)
{
    __shared__ unsigned short tS[TI * LN];            // 32 KiB T (swizzled, R7 layout)
    const int tid    = threadIdx.x;
    const int wv     = __builtin_amdgcn_readfirstlane(tid >> 6);   // wave id 0..7
    const int lane   = tid & 63;
    const int i_base = blockIdx.x * TI;
    char* tB = (char*)tS;
    const unsigned lane4 = (unsigned)lane * 4u;

    // ---------------- stage 1: 2 rows per wave ----------------
    for (int it = 0; it < 2; ++it) {
        const int row = wv * 2 + it;                  // uniform 0..15
        const int i   = i_base + row;
        const int*   nl = nlist + (size_t)i * KNB;
        const float* ep = edges + (size_t)i * (KNB * E);

        float a0[E], a1[E];
        #pragma unroll
        for (int n = 0; n < E; ++n) { a0[n] = 0.f; a1[n] = 0.f; }

        unsigned g[32];
        unsigned vo[8];
        MKVO(0);  ISSUE8(0);                          //  8 in flight
        MKVO(8);  ISSUE8(8);                          // 16 in flight
        MKVO(16); ISSUE8(16);                         // 24 in flight
        WAIT8("16", 0);  CONSUME8(0);                 // b0 landed; b1,b2 flying
        MKVO(24); ISSUE8(24);                         // b1,b2,b3 flying (<=24)
        WAIT8("16", 8);  CONSUME8(8);                 // b1 landed; b2,b3 flying
        WAIT8("8", 16);  CONSUME8(16);                // b2 landed; b3 flying
        WAIT8("0", 24);  CONSUME8(24);                // all done

        // pack 16 bf16 (ln = lane*16 + 0..15 of row), swizzled 16B-slot store (R7)
        uint4 pk0, pk1;
        asm("v_cvt_pk_bf16_f32 %0, %1, %2" : "=v"(pk0.x) : "v"(a0[0]), "v"(a0[1]));
        asm("v_cvt_pk_bf16_f32 %0, %1, %2" : "=v"(pk0.y) : "v"(a0[2]), "v"(a0[3]));
        asm("v_cvt_pk_bf16_f32 %0, %1, %2" : "=v"(pk0.z) : "v"(a0[4]), "v"(a0[5]));
        asm("v_cvt_pk_bf16_f32 %0, %1, %2" : "=v"(pk0.w) : "v"(a0[6]), "v"(a0[7]));
        asm("v_cvt_pk_bf16_f32 %0, %1, %2" : "=v"(pk1.x) : "v"(a1[0]), "v"(a1[1]));
        asm("v_cvt_pk_bf16_f32 %0, %1, %2" : "=v"(pk1.y) : "v"(a1[2]), "v"(a1[3]));
        asm("v_cvt_pk_bf16_f32 %0, %1, %2" : "=v"(pk1.z) : "v"(a1[4]), "v"(a1[5]));
        asm("v_cvt_pk_bf16_f32 %0, %1, %2" : "=v"(pk1.w) : "v"(a1[6]), "v"(a1[7]));
        const int p2 = (lane >> 2) & 1;
        const int s  = (row & 7) << 4;
        const int rb = row * (LN * 2);
        const uint4 first  = p2 ? pk1 : pk0;
        const uint4 second = p2 ? pk0 : pk1;
        *(uint4*)(tB + rb + ((lane * 32 + (p2 << 4))      ^ s)) = first;
        *(uint4*)(tB + rb + ((lane * 32 + 16 - (p2 << 4)) ^ s)) = second;
    }
    __syncthreads();

    // ---------------- stage 2: MFMA, one 16x16 m-tile per wave (R7 verbatim) ----------------
    const int colm = lane & 15;                       // i-row for A, m-col for B/C
    const int kq   = lane >> 4;
    const int mt   = wv;                              // m-tile 0..7

    f32x4 c0 = {0.f, 0.f, 0.f, 0.f};

    const int arow = colm * (LN * 2);
    const int asw  = (colm & 7) << 4;

    #pragma unroll 4
    for (int kb = 0; kb < LN / 32; ++kb) {
        union { short8v v; uint2 u[2]; } af;
        af.u[0] = *(const uint2*)(tB + arow + ((kb * 64      + kq * 8) ^ asw)); // k=kb*32+kq*4+e
        af.u[1] = *(const uint2*)(tB + arow + ((kb * 64 + 32 + kq * 8) ^ asw)); // k=kb*32+16+kq*4+e
        union { short8v v; uint4 u; } b0;
        b0.u = *(const uint4*)(w2f + ((size_t)((kb * 128 + mt * 16 + colm) * 4 + kq)) * 8);
        c0 = __builtin_amdgcn_mfma_f32_16x16x32_bf16(af.v, b0.v, c0, 0, 0, 0);
    }

    // C/D: col = lane&15, row = (lane>>4)*4 + r   [measured m89]
    #pragma unroll
    for (int r = 0; r < 4; ++r) {
        const int ii = kq * 4 + r;
        const int gi = i_base + ii;
        out[(size_t)gi * F + mt * 16 + colm] = inv_degree[gi] * c0[r];
    }
}

// ---------- fallback (round-1 kernel, pure fp32) for tiny ws ----------
__global__ __launch_bounds__(256, 2)
void mp_fused_fallback(const float* __restrict__ nodes, const int* __restrict__ nlist,
                       const float* __restrict__ edges, const float* __restrict__ inv_degree,
                       const float* __restrict__ w, float* __restrict__ out)
{
    __shared__ float tLds[TI * F * E];
    const int tid = threadIdx.x;
    const int i_base = blockIdx.x * TI;
    {
        const int l = tid & (F - 1);
        const int half = __builtin_amdgcn_readfirstlane(tid >> 7);
        for (int g = 0; g < TI / 2; ++g) {
            const int ii = g * 2 + half;
            const int i = i_base + ii;
            float acc[E];
            #pragma unroll
            for (int n = 0; n < E; ++n) acc[n] = 0.f;
            const int* nl = nlist + i * KNB;
            const float* ep = edges + (size_t)i * (KNB * E);
            #pragma unroll 4
            for (int j = 0; j < KNB; ++j) {
                unsigned idx = (unsigned)nl[j];
                if (idx >= (unsigned)NN) idx = 0u;
                const float v = nodes[idx * F + l];
                #pragma unroll
                for (int n = 0; n < E; ++n) acc[n] = __builtin_fmaf(ep[j * E + n], v, acc[n]);
            }
            float4* dst = (float4*)&tLds[ii * (F * E) + l * E];
            dst[0] = make_float4(acc[0], acc[1], acc[2], acc[3]);
            dst[1] = make_float4(acc[4], acc[5], acc[6], acc[7]);
        }
    }
    __syncthreads();
    const int m_lo = tid & 63;
    const int q = __builtin_amdgcn_readfirstlane(tid >> 6);
    float accA[TI], accB[TI];
    #pragma unroll
    for (int ii = 0; ii < TI; ++ii) { accA[ii] = 0.f; accB[ii] = 0.f; }
    for (int lq = 0; lq < F / 4; ++lq) {
        const int l = q * (F / 4) + lq;
        const float4* wp0 = (const float4*)&w[(size_t)l * (F * E) + (size_t)m_lo * E];
        const float4* wp1 = (const float4*)&w[(size_t)l * (F * E) + (size_t)(m_lo + 64) * E];
        const float4 w0a = wp0[0], w0b = wp0[1];
        const float4 w1a = wp1[0], w1b = wp1[1];
        #pragma unroll
        for (int ii = 0; ii < TI; ++ii) {
            const float4* tp = (const float4*)&tLds[ii * (F * E) + l * E];
            const float4 ta = tp[0], tb = tp[1];
            float sA = accA[ii], sB = accB[ii];
            sA = __builtin_fmaf(ta.x, w0a.x, sA); sA = __builtin_fmaf(ta.y, w0a.y, sA);
            sA = __builtin_fmaf(ta.z, w0a.z, sA); sA = __builtin_fmaf(ta.w, w0a.w, sA);
            sA = __builtin_fmaf(tb.x, w0b.x, sA); sA = __builtin_fmaf(tb.y, w0b.y, sA);
            sA = __builtin_fmaf(tb.z, w0b.z, sA); sA = __builtin_fmaf(tb.w, w0b.w, sA);
            sB = __builtin_fmaf(ta.x, w1a.x, sB); sB = __builtin_fmaf(ta.y, w1a.y, sB);
            sB = __builtin_fmaf(ta.z, w1a.z, sB); sB = __builtin_fmaf(ta.w, w1a.w, sB);
            sB = __builtin_fmaf(tb.x, w1b.x, sB); sB = __builtin_fmaf(tb.y, w1b.y, sB);
            sB = __builtin_fmaf(tb.z, w1b.z, sB); sB = __builtin_fmaf(tb.w, w1b.w, sB);
            accA[ii] = sA; accB[ii] = sB;
        }
    }
    __syncthreads();
    float* pLds = tLds;
    #pragma unroll
    for (int ii = 0; ii < TI; ++ii) {
        pLds[q * (TI * F) + ii * F + m_lo] = accA[ii];
        pLds[q * (TI * F) + ii * F + m_lo + 64] = accB[ii];
    }
    __syncthreads();
    #pragma unroll
    for (int r = 0; r < (TI * F) / 256; ++r) {
        const int o = r * 256 + tid;
        const int ii = o >> 7;
        const int m = o & (F - 1);
        const float s = pLds[0 * (TI * F) + ii * F + m] + pLds[1 * (TI * F) + ii * F + m]
                      + pLds[2 * (TI * F) + ii * F + m] + pLds[3 * (TI * F) + ii * F + m];
        const int i = i_base + ii;
        out[(size_t)i * F + m] = inv_degree[i] * s;
    }
}

extern "C" void kernel_launch(void* const* d_in, const int* in_sizes, int n_in,
                              void* d_out, int out_size, void* d_ws, size_t ws_size,
                              hipStream_t stream) {
    const float* nodes      = (const float*)d_in[0];
    const int*   nlist      = (const int*)d_in[1];
    const float* edges      = (const float*)d_in[2];
    const float* inv_degree = (const float*)d_in[3];
    const float* w          = (const float*)d_in[4];
    float* out = (float*)d_out;
    (void)in_sizes; (void)n_in; (void)out_size;

    const size_t need_w2 = (size_t)LN * F * 2;                  // 256 KiB
    const size_t need_nb = (size_t)NN * F * 2;                  // 12.8 MiB

    if (ws_size < need_w2 + need_nb) {
        mp_fused_fallback<<<dim3(NN / TI), dim3(256), 0, stream>>>(
            nodes, nlist, edges, inv_degree, w, out);
        return;
    }
    unsigned short* w2f = (unsigned short*)d_ws;
    unsigned short* nb  = (unsigned short*)((char*)d_ws + need_w2);

    prep_w_kernel<<<dim3((LN * F) / 256), dim3(256), 0, stream>>>(w, w2f);
    prep_nodes_kernel<<<dim3(NN * F / 8 / 256), dim3(256), 0, stream>>>(nodes, nb);
    mp_main_kernel<<<dim3(NN / TI), dim3(512), 0, stream>>>(
        nb, nlist, edges, inv_degree, w2f, out);
}

// Round 14
// 94.305 us; speedup vs baseline: 1.2388x; 1.0895x over previous
//
#include <hip/hip_runtime.h>
#include <hip/hip_bf16.h>

static constexpr int NN  = 50000;  // nodes
static constexpr int KNB = 32;     // neighbors
static constexpr int F   = 128;    // features
static constexpr int E   = 8;      // edge features
static constexpr int TI  = 16;     // nodes per block (3125 blocks)
static constexpr int LN  = F * E;  // 1024 contraction length

typedef __attribute__((ext_vector_type(8))) short short8v;
typedef __attribute__((ext_vector_type(4))) float f32x4;

__device__ __forceinline__ unsigned short f2bf(float x) {
    unsigned u = __float_as_uint(x);
    unsigned r = (u + 0x7fff + ((u >> 16) & 1)) >> 16;   // RNE
    return (unsigned short)r;
}
__device__ __forceinline__ float bf2f_lo(unsigned g) { return __uint_as_float(g << 16); }
__device__ __forceinline__ float bf2f_hi(unsigned g) { return __uint_as_float(g & 0xffff0000u); }

// ---------- prep A: w[l,m,n] -> W2f bf16 in B-fragment order ----------
// W2f[((kb*128 + m)*4 + kq)*8 + e8] = bf16( w[l,m,n] ) where
//   k = kb*32 + kq*4 + (e8&3) + (e8>>2)*16 ,  l = k>>3, n = k&7
__global__ void prep_w_kernel(const float* __restrict__ w, unsigned short* __restrict__ w2f) {
    int o  = blockIdx.x * 256 + threadIdx.x;          // 131072 total
    int e8 = o & 7, kq = (o >> 3) & 3, m = (o >> 5) & 127, kb = o >> 12;
    int k  = kb * 32 + kq * 4 + (e8 & 3) + ((e8 >> 2) << 4);
    int l  = k >> 3, n = k & 7;
    w2f[o] = f2bf(w[(size_t)(l * F + m) * E + n]);
}

// ---------- prep B: nodes fp32 -> bf16 (3125 blocks x 256 thr x 8 elems = exact) ----------
__global__ void prep_nodes_kernel(const float* __restrict__ nodes, unsigned short* __restrict__ nb) {
    int t = blockIdx.x * 256 + threadIdx.x;
    const float4* s = (const float4*)nodes + (size_t)t * 2;
    float4 a = s[0], b = s[1];
    uint4 pk;
    pk.x = (unsigned)f2bf(a.x) | ((unsigned)f2bf(a.y) << 16);
    pk.y = (unsigned)f2bf(a.z) | ((unsigned)f2bf(a.w) << 16);
    pk.z = (unsigned)f2bf(b.x) | ((unsigned)f2bf(b.y) << 16);
    pk.w = (unsigned)f2bf(b.z) | ((unsigned)f2bf(b.w) << 16);
    ((uint4*)nb)[t] = pk;
}

// Early-clobber ("=&v") is REQUIRED: multi-instruction asm; without it an
// output may alias a later instruction's address input (R12 crash).
#define ISSUE8(GB)                                                         \
    asm volatile(                                                          \
        "global_load_dword %0, %8, %16\n\t"                                \
        "global_load_dword %1, %9, %16\n\t"                                \
        "global_load_dword %2, %10, %16\n\t"                               \
        "global_load_dword %3, %11, %16\n\t"                               \
        "global_load_dword %4, %12, %16\n\t"                               \
        "global_load_dword %5, %13, %16\n\t"                               \
        "global_load_dword %6, %14, %16\n\t"                               \
        "global_load_dword %7, %15, %16"                                   \
        : "=&v"(g[(GB)+0]), "=&v"(g[(GB)+1]), "=&v"(g[(GB)+2]), "=&v"(g[(GB)+3]), \
          "=&v"(g[(GB)+4]), "=&v"(g[(GB)+5]), "=&v"(g[(GB)+6]), "=&v"(g[(GB)+7])  \
        : "v"(vo[0]), "v"(vo[1]), "v"(vo[2]), "v"(vo[3]),                  \
          "v"(vo[4]), "v"(vo[5]), "v"(vo[6]), "v"(vo[7]),                  \
          "s"(nodesBf)                                                     \
        : "memory")

#define MKVO(JB)                                                           \
    _Pragma("unroll")                                                      \
    for (int q = 0; q < 8; ++q) {                                          \
        unsigned idx = (unsigned)nl[(JB) + q];     /* uniform -> s_load */ \
        if (idx >= (unsigned)NN) idx = 0u;                                 \
        vo[q] = idx * 256u + lane4;                                        \
    }

#define WAIT8(NSTR, GB)                                                    \
    asm volatile("s_waitcnt vmcnt(" NSTR ")"                               \
        : "+v"(g[(GB)+0]), "+v"(g[(GB)+1]), "+v"(g[(GB)+2]), "+v"(g[(GB)+3]),  \
          "+v"(g[(GB)+4]), "+v"(g[(GB)+5]), "+v"(g[(GB)+6]), "+v"(g[(GB)+7])   \
        :: "memory")

#define CONSUME8(JB, GB)                                                   \
    _Pragma("unroll")                                                      \
    for (int q = 0; q < 8; ++q) {                                          \
        const int j = (JB) + q;                                            \
        const float v0 = bf2f_lo(g[(GB) + q]);                             \
        const float v1 = bf2f_hi(g[(GB) + q]);                             \
        const float4 e0 = *(const float4*)(ep + j * 8);   /* uniform */    \
        const float4 e1 = *(const float4*)(ep + j * 8 + 4);                \
        a0[0] = __builtin_fmaf(e0.x, v0, a0[0]); a1[0] = __builtin_fmaf(e0.x, v1, a1[0]); \
        a0[1] = __builtin_fmaf(e0.y, v0, a0[1]); a1[1] = __builtin_fmaf(e0.y, v1, a1[1]); \
        a0[2] = __builtin_fmaf(e0.z, v0, a0[2]); a1[2] = __builtin_fmaf(e0.z, v1, a1[2]); \
        a0[3] = __builtin_fmaf(e0.w, v0, a0[3]); a1[3] = __builtin_fmaf(e0.w, v1, a1[3]); \
        a0[4] = __builtin_fmaf(e1.x, v0, a0[4]); a1[4] = __builtin_fmaf(e1.x, v1, a1[4]); \
        a0[5] = __builtin_fmaf(e1.y, v0, a0[5]); a1[5] = __builtin_fmaf(e1.y, v1, a1[5]); \
        a0[6] = __builtin_fmaf(e1.z, v0, a0[6]); a1[6] = __builtin_fmaf(e1.z, v1, a1[6]); \
        a0[7] = __builtin_fmaf(e1.w, v0, a0[7]); a1[7] = __builtin_fmaf(e1.w, v1, a1[7]); \
    }

// ---------- main fused kernel ----------
// R7 structure (512 thr / 8 waves, T 32 KiB swizzled, stage-2 verbatim).
// Stage 1: per row, 16-deep rolling gather window: 2 live bursts of 8
// global_load_dword (forced via inline asm), counted vmcnt(8) rolls, g-slot
// reuse after consumption. Sized to fit 64 regs -> 4 blocks/CU.
__global__ __launch_bounds__(512, 8)
void mp_main_kernel(const unsigned short* __restrict__ nodesBf,
                    const int*   __restrict__ nlist,
                    const float* __restrict__ edges,
                    const float* __restrict__ inv_degree,
                    const unsigned short* __restrict__ w2f,
                    float* __restrict__ out)
{
    __shared__ unsigned short tS[TI * LN];            // 32 KiB T (swizzled, R7 layout)
    const int tid    = threadIdx.x;
    const int wv     = __builtin_amdgcn_readfirstlane(tid >> 6);   // wave id 0..7
    const int lane   = tid & 63;
    const int i_base = blockIdx.x * TI;
    char* tB = (char*)tS;
    const unsigned lane4 = (unsigned)lane * 4u;

    // ---------------- stage 1: 2 rows per wave ----------------
    for (int it = 0; it < 2; ++it) {
        const int row = wv * 2 + it;                  // uniform 0..15
        const int i   = i_base + row;
        const int*   nl = nlist + (size_t)i * KNB;
        const float* ep = edges + (size_t)i * (KNB * E);

        float a0[E], a1[E];
        #pragma unroll
        for (int n = 0; n < E; ++n) { a0[n] = 0.f; a1[n] = 0.f; }

        unsigned g[16];
        unsigned vo[8];
        MKVO(0);  ISSUE8(0);                          //  8 in flight (j 0-7)
        MKVO(8);  ISSUE8(8);                          // 16 in flight (j 8-15)
        WAIT8("8", 0);  CONSUME8(0, 0);               // j0-7 landed; 8 flying
        MKVO(16); ISSUE8(0);                          // 16 in flight (j16-23 -> g[0..7])
        WAIT8("8", 8);  CONSUME8(8, 8);               // j8-15 landed; 8 flying
        MKVO(24); ISSUE8(8);                          // 16 in flight (j24-31 -> g[8..15])
        WAIT8("8", 0);  CONSUME8(16, 0);              // j16-23 landed; 8 flying
        WAIT8("0", 8);  CONSUME8(24, 8);              // all done

        // pack 16 bf16 (ln = lane*16 + 0..15 of row), swizzled 16B-slot store (R7)
        uint4 pk0, pk1;
        asm("v_cvt_pk_bf16_f32 %0, %1, %2" : "=v"(pk0.x) : "v"(a0[0]), "v"(a0[1]));
        asm("v_cvt_pk_bf16_f32 %0, %1, %2" : "=v"(pk0.y) : "v"(a0[2]), "v"(a0[3]));
        asm("v_cvt_pk_bf16_f32 %0, %1, %2" : "=v"(pk0.z) : "v"(a0[4]), "v"(a0[5]));
        asm("v_cvt_pk_bf16_f32 %0, %1, %2" : "=v"(pk0.w) : "v"(a0[6]), "v"(a0[7]));
        asm("v_cvt_pk_bf16_f32 %0, %1, %2" : "=v"(pk1.x) : "v"(a1[0]), "v"(a1[1]));
        asm("v_cvt_pk_bf16_f32 %0, %1, %2" : "=v"(pk1.y) : "v"(a1[2]), "v"(a1[3]));
        asm("v_cvt_pk_bf16_f32 %0, %1, %2" : "=v"(pk1.z) : "v"(a1[4]), "v"(a1[5]));
        asm("v_cvt_pk_bf16_f32 %0, %1, %2" : "=v"(pk1.w) : "v"(a1[6]), "v"(a1[7]));
        const int p2 = (lane >> 2) & 1;
        const int s  = (row & 7) << 4;
        const int rb = row * (LN * 2);
        const uint4 first  = p2 ? pk1 : pk0;
        const uint4 second = p2 ? pk0 : pk1;
        *(uint4*)(tB + rb + ((lane * 32 + (p2 << 4))      ^ s)) = first;
        *(uint4*)(tB + rb + ((lane * 32 + 16 - (p2 << 4)) ^ s)) = second;
    }
    __syncthreads();

    // ---------------- stage 2: MFMA, one 16x16 m-tile per wave (R7 verbatim) ----------------
    const int colm = lane & 15;                       // i-row for A, m-col for B/C
    const int kq   = lane >> 4;
    const int mt   = wv;                              // m-tile 0..7

    f32x4 c0 = {0.f, 0.f, 0.f, 0.f};

    const int arow = colm * (LN * 2);
    const int asw  = (colm & 7) << 4;

    #pragma unroll 4
    for (int kb = 0; kb < LN / 32; ++kb) {
        union { short8v v; uint2 u[2]; } af;
        af.u[0] = *(const uint2*)(tB + arow + ((kb * 64      + kq * 8) ^ asw)); // k=kb*32+kq*4+e
        af.u[1] = *(const uint2*)(tB + arow + ((kb * 64 + 32 + kq * 8) ^ asw)); // k=kb*32+16+kq*4+e
        union { short8v v; uint4 u; } b0;
        b0.u = *(const uint4*)(w2f + ((size_t)((kb * 128 + mt * 16 + colm) * 4 + kq)) * 8);
        c0 = __builtin_amdgcn_mfma_f32_16x16x32_bf16(af.v, b0.v, c0, 0, 0, 0);
    }

    // C/D: col = lane&15, row = (lane>>4)*4 + r   [measured m89]
    #pragma unroll
    for (int r = 0; r < 4; ++r) {
        const int ii = kq * 4 + r;
        const int gi = i_base + ii;
        out[(size_t)gi * F + mt * 16 + colm] = inv_degree[gi] * c0[r];
    }
}

// ---------- fallback (round-1 kernel, pure fp32) for tiny ws ----------
__global__ __launch_bounds__(256, 2)
void mp_fused_fallback(const float* __restrict__ nodes, const int* __restrict__ nlist,
                       const float* __restrict__ edges, const float* __restrict__ inv_degree,
                       const float* __restrict__ w, float* __restrict__ out)
{
    __shared__ float tLds[TI * F * E];
    const int tid = threadIdx.x;
    const int i_base = blockIdx.x * TI;
    {
        const int l = tid & (F - 1);
        const int half = __builtin_amdgcn_readfirstlane(tid >> 7);
        for (int g = 0; g < TI / 2; ++g) {
            const int ii = g * 2 + half;
            const int i = i_base + ii;
            float acc[E];
            #pragma unroll
            for (int n = 0; n < E; ++n) acc[n] = 0.f;
            const int* nl = nlist + i * KNB;
            const float* ep = edges + (size_t)i * (KNB * E);
            #pragma unroll 4
            for (int j = 0; j < KNB; ++j) {
                unsigned idx = (unsigned)nl[j];
                if (idx >= (unsigned)NN) idx = 0u;
                const float v = nodes[idx * F + l];
                #pragma unroll
                for (int n = 0; n < E; ++n) acc[n] = __builtin_fmaf(ep[j * E + n], v, acc[n]);
            }
            float4* dst = (float4*)&tLds[ii * (F * E) + l * E];
            dst[0] = make_float4(acc[0], acc[1], acc[2], acc[3]);
            dst[1] = make_float4(acc[4], acc[5], acc[6], acc[7]);
        }
    }
    __syncthreads();
    const int m_lo = tid & 63;
    const int q = __builtin_amdgcn_readfirstlane(tid >> 6);
    float accA[TI], accB[TI];
    #pragma unroll
    for (int ii = 0; ii < TI; ++ii) { accA[ii] = 0.f; accB[ii] = 0.f; }
    for (int lq = 0; lq < F / 4; ++lq) {
        const int l = q * (F / 4) + lq;
        const float4* wp0 = (const float4*)&w[(size_t)l * (F * E) + (size_t)m_lo * E];
        const float4* wp1 = (const float4*)&w[(size_t)l * (F * E) + (size_t)(m_lo + 64) * E];
        const float4 w0a = wp0[0], w0b = wp0[1];
        const float4 w1a = wp1[0], w1b = wp1[1];
        #pragma unroll
        for (int ii = 0; ii < TI; ++ii) {
            const float4* tp = (const float4*)&tLds[ii * (F * E) + l * E];
            const float4 ta = tp[0], tb = tp[1];
            float sA = accA[ii], sB = accB[ii];
            sA = __builtin_fmaf(ta.x, w0a.x, sA); sA = __builtin_fmaf(ta.y, w0a.y, sA);
            sA = __builtin_fmaf(ta.z, w0a.z, sA); sA = __builtin_fmaf(ta.w, w0a.w, sA);
            sA = __builtin_fmaf(tb.x, w0b.x, sA); sA = __builtin_fmaf(tb.y, w0b.y, sA);
            sA = __builtin_fmaf(tb.z, w0b.z, sA); sA = __builtin_fmaf(tb.w, w0b.w, sA);
            sB = __builtin_fmaf(ta.x, w1a.x, sB); sB = __builtin_fmaf(ta.y, w1a.y, sB);
            sB = __builtin_fmaf(ta.z, w1a.z, sB); sB = __builtin_fmaf(ta.w, w1a.w, sB);
            sB = __builtin_fmaf(tb.x, w1b.x, sB); sB = __builtin_fmaf(tb.y, w1b.y, sB);
            sB = __builtin_fmaf(tb.z, w1b.z, sB); sB = __builtin_fmaf(tb.w, w1b.w, sB);
            accA[ii] = sA; accB[ii] = sB;
        }
    }
    __syncthreads();
    float* pLds = tLds;
    #pragma unroll
    for (int ii = 0; ii < TI; ++ii) {
        pLds[q * (TI * F) + ii * F + m_lo] = accA[ii];
        pLds[q * (TI * F) + ii * F + m_lo + 64] = accB[ii];
    }
    __syncthreads();
    #pragma unroll
    for (int r = 0; r < (TI * F) / 256; ++r) {
        const int o = r * 256 + tid;
        const int ii = o >> 7;
        const int m = o & (F - 1);
        const float s = pLds[0 * (TI * F) + ii * F + m] + pLds[1 * (TI * F) + ii * F + m]
                      + pLds[2 * (TI * F) + ii * F + m] + pLds[3 * (TI * F) + ii * F + m];
        const int i = i_base + ii;
        out[(size_t)i * F + m] = inv_degree[i] * s;
    }
}

extern "C" void kernel_launch(void* const* d_in, const int* in_sizes, int n_in,
                              void* d_out, int out_size, void* d_ws, size_t ws_size,
                              hipStream_t stream) {
    const float* nodes      = (const float*)d_in[0];
    const int*   nlist      = (const int*)d_in[1];
    const float* edges      = (const float*)d_in[2];
    const float* inv_degree = (const float*)d_in[3];
    const float* w          = (const float*)d_in[4];
    float* out = (float*)d_out;
    (void)in_sizes; (void)n_in; (void)out_size;

    const size_t need_w2 = (size_t)LN * F * 2;                  // 256 KiB
    const size_t need_nb = (size_t)NN * F * 2;                  // 12.8 MiB

    if (ws_size < need_w2 + need_nb) {
        mp_fused_fallback<<<dim3(NN / TI), dim3(256), 0, stream>>>(
            nodes, nlist, edges, inv_degree, w, out);
        return;
    }
    unsigned short* w2f = (unsigned short*)d_ws;
    unsigned short* nb  = (unsigned short*)((char*)d_ws + need_w2);

    prep_w_kernel<<<dim3((LN * F) / 256), dim3(256), 0, stream>>>(w, w2f);
    prep_nodes_kernel<<<dim3(NN * F / 8 / 256), dim3(256), 0, stream>>>(nodes, nb);
    mp_main_kernel<<<dim3(NN / TI), dim3(512), 0, stream>>>(
        nb, nlist, edges, inv_degree, w2f, out);
}